// Round 1
// 309.954 us; speedup vs baseline: 1.0289x; 1.0289x over previous
//
#include <hip/hip_runtime.h>
#include <cstdint>
#include <cstring>
#include <cmath>

// SpecAugment masking of x:(B=128,F=128,T=3000) float32 (in & out f32).
// Masks are deterministic (jax.random.key(42)); reproduced EXACTLY on host
// using the *partitionable* threefry scheme (jax_threefry_partitionable=True,
// the default since jax 0.4.30):
//   - split (fold-like): child i of key k = cipher pair tf2x32(k, (0, i))
//   - random_bits(key, 32, (n,)): elem b -> o0 ^ o1 of tf2x32(key, (0, b))
//   - randint(key,(n,),0,s): k1,k2 = split(key); hi=bits(k1,b); lo=bits(k2,b);
//       m=(2^16%s)^2%s;  off = ((hi%s)*m + lo%s) % s
//   - uniform(key,(n,)): u = bitcast((bits>>9)|0x3F800000) - 1.0
#define NB 128
#define NF 128
#define NT 3000
#define NT4 (NT / 4)   // 750 float4 per (b,f) row
#define F_MAG 40
#define T_MAG 100

typedef float f32x4 __attribute__((ext_vector_type(4)));

// -------- Threefry-2x32 (20 rounds, Random123/jax-exact) --------
static inline uint32_t rotl32(uint32_t v, int d) { return (v << d) | (v >> (32 - d)); }

static void tf2x32(uint32_t k0, uint32_t k1, uint32_t x0, uint32_t x1,
                   uint32_t* o0, uint32_t* o1) {
  const uint32_t ks2 = k0 ^ k1 ^ 0x1BD11BDAu;
  static const int R0[4] = {13, 15, 26, 6};
  static const int R1[4] = {17, 29, 16, 24};
  x0 += k0; x1 += k1;
  for (int i = 0; i < 4; i++) { x0 += x1; x1 = rotl32(x1, R0[i]); x1 ^= x0; }
  x0 += k1; x1 += ks2 + 1u;
  for (int i = 0; i < 4; i++) { x0 += x1; x1 = rotl32(x1, R1[i]); x1 ^= x0; }
  x0 += ks2; x1 += k0 + 2u;
  for (int i = 0; i < 4; i++) { x0 += x1; x1 = rotl32(x1, R0[i]); x1 ^= x0; }
  x0 += k0; x1 += k1 + 3u;
  for (int i = 0; i < 4; i++) { x0 += x1; x1 = rotl32(x1, R1[i]); x1 ^= x0; }
  x0 += k1; x1 += ks2 + 4u;
  for (int i = 0; i < 4; i++) { x0 += x1; x1 = rotl32(x1, R0[i]); x1 ^= x0; }
  x0 += ks2; x1 += k0 + 5u;
  *o0 = x0; *o1 = x1;
}

// Fold-like split (partitionable): children 0 and 1 of key (k0,k1).
static inline void pt_split2(uint32_t k0, uint32_t k1,
                             uint32_t* a0, uint32_t* a1,
                             uint32_t* b0, uint32_t* b1) {
  tf2x32(k0, k1, 0u, 0u, a0, a1);   // child 0 = (bits1[0], bits2[0])
  tf2x32(k0, k1, 0u, 1u, b0, b1);   // child 1
}

// Partitionable 32-bit random_bits: element i -> bits1 ^ bits2, counter (0, i).
static inline uint32_t pt_bits(uint32_t k0, uint32_t k1, uint32_t i) {
  uint32_t o0, o1;
  tf2x32(k0, k1, 0u, i, &o0, &o1);
  return o0 ^ o1;
}

// Per-batch band [lo, hi) over `size`, width = randint(0, max_width),
// start = floor(uniform * (size - w)) — exact f32 arithmetic.
static void band_params(uint32_t key0, uint32_t key1, int size, int max_width,
                        unsigned short* lo, unsigned short* hi) {
  uint32_t kw0, kw1, ku0, ku1;
  pt_split2(key0, key1, &kw0, &kw1, &ku0, &ku1);   // k_w, k_u = split(key)

  uint32_t ka0, ka1, kb0, kb1;                     // randint internal split
  pt_split2(kw0, kw1, &ka0, &ka1, &kb0, &kb1);     // k1 (higher), k2 (lower)

  const uint32_t s = (uint32_t)max_width;
  uint32_t m = 65536u % s;
  m = (m * m) % s;                                 // = 2^32 % s

  for (int b = 0; b < NB; b++) {
    uint32_t hb = pt_bits(ka0, ka1, (uint32_t)b);
    uint32_t lb = pt_bits(kb0, kb1, (uint32_t)b);
    uint32_t w = ((hb % s) * m + (lb % s)) % s;    // randint(0, max_width)

    uint32_t ub = pt_bits(ku0, ku1, (uint32_t)b);
    uint32_t fbits = (ub >> 9) | 0x3F800000u;      // uniform [0,1)
    float u;
    memcpy(&u, &fbits, 4);
    u -= 1.0f;
    if (u < 0.0f) u = 0.0f;                        // lax.max(minval, ...)

    int w0 = (int)floorf(u * (float)(size - (int)w));
    lo[b] = (unsigned short)w0;
    hi[b] = (unsigned short)(w0 + (int)w);
  }
}

// -------- Device kernel: f32, zero-or-passthrough (bit-exact) --------
struct MaskParams {
  unsigned short fl[NB], fh[NB];  // f-band [fl, fh) per batch
  unsigned short tl[NB], th[NB];  // t-band [tl, th) per batch
};

__device__ __forceinline__ f32x4 tmask4(f32x4 v, int t0, int tl, int th) {
  v.x = (t0     >= tl && t0     < th) ? 0.f : v.x;
  v.y = (t0 + 1 >= tl && t0 + 1 < th) ? 0.f : v.y;
  v.z = (t0 + 2 >= tl && t0 + 2 < th) ? 0.f : v.z;
  v.w = (t0 + 3 >= tl && t0 + 3 < th) ? 0.f : v.w;
  return v;
}

// One block per (b,f) row. 750 float4 = 2*256 + 238: each thread owns up to
// 3 slots, fully unrolled so all loads issue before any store (ILP), and all
// global traffic is nontemporal (zero reuse -> don't allocate in L2/L3).
__global__ __launch_bounds__(256) void specaug_kernel(
    const f32x4* __restrict__ x, f32x4* __restrict__ out, MaskParams p) {
  const int row = blockIdx.x;      // 0 .. NB*NF-1, one block per (b,f) row
  const int b = row >> 7;
  const int f = row & (NF - 1);
  const int i0 = threadIdx.x;
  const bool has3 = (i0 < NT4 - 512);  // i0 < 238

  const f32x4* __restrict__ px = x + (long)row * NT4;
  f32x4* __restrict__ po = out + (long)row * NT4;

  const bool frow = (f >= (int)p.fl[b]) && (f < (int)p.fh[b]);
  if (frow) {
    // Entire row masked: skip the global read, stream zeros.
    const f32x4 z = {0.f, 0.f, 0.f, 0.f};
    __builtin_nontemporal_store(z, po + i0);
    __builtin_nontemporal_store(z, po + i0 + 256);
    if (has3) __builtin_nontemporal_store(z, po + i0 + 512);
    return;
  }

  // Issue all loads up front.
  f32x4 v0 = __builtin_nontemporal_load(px + i0);
  f32x4 v1 = __builtin_nontemporal_load(px + i0 + 256);
  f32x4 v2 = {0.f, 0.f, 0.f, 0.f};
  if (has3) v2 = __builtin_nontemporal_load(px + i0 + 512);

  const int tl = (int)p.tl[b], th = (int)p.th[b];
  v0 = tmask4(v0, 4 * i0,         tl, th);
  v1 = tmask4(v1, 4 * (i0 + 256), tl, th);
  v2 = tmask4(v2, 4 * (i0 + 512), tl, th);

  __builtin_nontemporal_store(v0, po + i0);
  __builtin_nontemporal_store(v1, po + i0 + 256);
  if (has3) __builtin_nontemporal_store(v2, po + i0 + 512);
}

extern "C" void kernel_launch(void* const* d_in, const int* in_sizes, int n_in,
                              void* d_out, int out_size, void* d_ws, size_t ws_size,
                              hipStream_t stream) {
  const f32x4* x = (const f32x4*)d_in[0];
  f32x4* out = (f32x4*)d_out;

  // Host-side mask derivation (pure CPU, graph-capture safe, identical
  // every call). Root key(42) = (0, 42); kf, kt = split(root) [fold-like].
  uint32_t kf0, kf1, kt0, kt1;
  pt_split2(0u, 42u, &kf0, &kf1, &kt0, &kt1);

  MaskParams p;
  band_params(kf0, kf1, NF, F_MAG, p.fl, p.fh);
  band_params(kt0, kt1, NT, T_MAG, p.tl, p.th);

  hipLaunchKernelGGL(specaug_kernel, dim3(NB * NF), dim3(256), 0, stream,
                     x, out, p);
}